// Round 13
// baseline (322.524 us; speedup 1.0000x reference)
//
#include <hip/hip_runtime.h>
#include <hip/hip_bf16.h>

typedef unsigned short u16;
typedef __attribute__((ext_vector_type(4))) unsigned short u16x4;
typedef __attribute__((ext_vector_type(8))) short short8;
typedef __attribute__((ext_vector_type(16))) float f32x16;

#define MFMA(a,b,c) __builtin_amdgcn_mfma_f32_32x32x16_bf16((a),(b),(c),0,0,0)

// ---- output offsets (floats), reference return order ----
static constexpr size_t OFF_XOUT = 0;
static constexpr size_t OFF_Z    = 16777216;
static constexpr size_t OFF_ZHAT = 20971520;
static constexpr size_t OFF_SUR  = 25165824;
static constexpr size_t OFF_KC   = 25296896;
static constexpr size_t OFF_VP   = 42074112;
static constexpr size_t OFF_GATE = 58851328;
static constexpr size_t OFF_QN   = 58982400;
static constexpr size_t OFF_VC   = 75759616;
static constexpr size_t OFF_WN   = 92536832;
static constexpr size_t OFF_S5   = 92667904;

// ---- workspace offsets (u16 elements): PRE-SWIZZLED bf16 weight images ----
static constexpr size_t WUP_I = 0;          // [G][4 chunks][32KB swz256 image of [128c][128k]]
static constexpr size_t WDN_I = 4194304;    // [G][4 chunks][32KB swz256 image of [128j][128c]]
static constexpr size_t WPO_I = 8388608;    // [G][4 slices][32KB image] + [128] nov col (65664/g)
static constexpr size_t WEN_I = 12591104;   // [G][8KB swz256 image of [32c][128k]]
static constexpr size_t WGN_I = 12853248;   // [G][8KB swz64 image of [128j][32k]]
static constexpr size_t WPR_I = 13115392;   // [G][2KB swz64 image of [32c][32k]]

// native RNE conversion — lets the compiler emit v_cvt(_pk)_bf16_f32
__device__ __forceinline__ u16 f2b(float f) {
    __hip_bfloat16 h = __float2bfloat16(f);
    u16 r; __builtin_memcpy(&r, &h, 2); return r;
}
__device__ __forceinline__ float b2f(u16 b) {
    return __uint_as_float(((unsigned)b) << 16);
}
__device__ __forceinline__ int swz256(int row, int b) {
    return row * 256 + (b ^ ((row & 7) << 4) ^ (((row >> 3) & 1) << 7));
}
__device__ __forceinline__ int swz64(int row, int b) {
    return row * 64 + (b ^ ((row & 3) << 4));
}
__device__ __forceinline__ short8 fragLd256(const u16* s, int row, int ks) {
    int b = ks * 32 + ((threadIdx.x >> 5) & 1) * 16;
    return *(const short8*)((const char*)s + swz256(row, b));
}
__device__ __forceinline__ short8 fragLd64(const u16* s, int row, int ks) {
    int b = ks * 32 + ((threadIdx.x >> 5) & 1) * 16;
    return *(const short8*)((const char*)s + swz64(row, b));
}
__device__ __forceinline__ float tanh_f(float x) {
    float xc = fminf(fmaxf(x, -15.f), 15.f);
    float e = __expf(2.f * xc);
    return __fdividef(e - 1.f, e + 1.f);
}
// sigmoid-gelu: u*sigma(1.702u)
__device__ __forceinline__ float gelu_f(float u) {
    return __fdividef(u, 1.f + __expf(-1.702f * u));
}

// dst element index inside a group's image for source element (k, c)
__device__ __forceinline__ size_t mapElem(int wt, int k, int c) {
    switch (wt) {
    case 0: return (size_t)(c >> 7) * 16384 + (swz256(c & 127, 2 * k) >> 1);          // W_up
    case 1: return (size_t)(k >> 7) * 16384 + (swz256(c, 2 * (k & 127)) >> 1);        // W_down
    case 2: return (c == 512) ? (size_t)65536 + k
                              : (size_t)(c >> 7) * 16384 + (swz256(c & 127, 2 * k) >> 1); // W_post
    case 3: return (size_t)(swz256(c, 2 * k) >> 1);                                   // W_enc
    case 4: return (size_t)(swz64(c, 2 * k) >> 1);                                    // W_gain
    default: return (size_t)(swz64(c, 2 * k) >> 1);                                   // W_pred
    }
}

// ---------------- transpose + convert + swizzle for all six weights ----------------
// 8 consecutive k at fixed c map to one aligned 16B block in every image
// (swizzle XOR bits are >= bit 4), so writes are vectorized short8 stores.
__global__ __launch_bounds__(256)
void kconv_all(const float* __restrict__ W_up, const float* __restrict__ W_down,
               const float* __restrict__ W_post, const float* __restrict__ W_enc,
               const float* __restrict__ W_gain, const float* __restrict__ W_pred,
               u16* __restrict__ ws)
{
    int b = blockIdx.x;
    const float* src; u16* dst; int K, C, bx, wt; size_t gstride;
    if (b < 1024)      { src = W_up;   dst = ws + WUP_I; K = 128; C = 512; bx = 8; wt = 0; gstride = 65536; }
    else if (b < 2048) { b -= 1024; src = W_down; dst = ws + WDN_I; K = 512; C = 128; bx = 2; wt = 1; gstride = 65536; }
    else if (b < 3200) { b -= 2048; src = W_post; dst = ws + WPO_I; K = 128; C = 513; bx = 9; wt = 2; gstride = 65664; }
    else if (b < 3328) { b -= 3200; src = W_enc;  dst = ws + WEN_I; K = 128; C = 32;  bx = 1; wt = 3; gstride = 4096; }
    else if (b < 3456) { b -= 3328; src = W_gain; dst = ws + WGN_I; K = 32;  C = 128; bx = 2; wt = 4; gstride = 4096; }
    else               { b -= 3456; src = W_pred; dst = ws + WPR_I; K = 32;  C = 32;  bx = 1; wt = 5; gstride = 1024; }
    const int by = (K + 63) >> 6;
    const int nb = bx * by;
    const int g = b / nb, r = b % nb;
    const int c0 = (r % bx) * 64, k0 = (r / bx) * 64;

    __shared__ float sT[64][65];
    const float* s = src + (size_t)g * K * C;
    u16* d = dst + (size_t)g * gstride;
    for (int e = threadIdx.x; e < 64 * 64; e += 256) {
        int kk = e >> 6, cc = e & 63;
        if (k0 + kk < K && c0 + cc < C)
            sT[kk][cc] = s[(size_t)(k0 + kk) * C + c0 + cc];
    }
    __syncthreads();
    // vectorized: 64 cols x 8 k-blocks per tile, one short8 store each
    for (int e = threadIdx.x; e < 512; e += 256) {
        int cc = e & 63, kb = e >> 6;
        int c = c0 + cc, k = k0 + kb * 8;
        if (c < C && c != 512 && k + 7 < K) {
            short8 v;
            #pragma unroll
            for (int i = 0; i < 8; ++i) v[i] = (short)f2b(sT[kb * 8 + i][cc]);
            *(short8*)(d + mapElem(wt, k, c)) = v;
        }
    }
    if (wt == 2 && c0 == 512) {   // nov column scalar path
        for (int kk = threadIdx.x; kk < 64; kk += 256) {
            int k = k0 + kk;
            if (k < K) d[(size_t)65536 + k] = f2b(sT[kk][0]);
        }
    }
}

// ---------------- fused main: r12 structure (T14 prefetch) + native cvt ----------------
__global__ __launch_bounds__(1024, 4)
void kfused(const float* __restrict__ x_col,
            const float* __restrict__ z_hat_prev,
            const float* __restrict__ gamma,
            const float* __restrict__ beta,
            const float* __restrict__ b_enc,
            const float* __restrict__ b_pred,
            const float* __restrict__ b_gain,
            const float* __restrict__ b_up,
            const float* __restrict__ b_down,
            const float* __restrict__ b_post,
            const u16* __restrict__ ws,
            float* __restrict__ out)
{
    const int bid = blockIdx.x;
    const int xc = bid & 7, j = bid >> 3;
    const int g = xc * 8 + (j >> 4);
    const int tile = j & 15;
    const int m0 = tile * 128;

    const int tid = threadIdx.x, lane = tid & 63;
    const int w16 = tid >> 6;                // wave 0..15
    const int wr = w16 >> 2;                 // row frag (32 rows)
    const int wc = w16 & 3;                  // col frag (32 cols)
    const int l31 = lane & 31, lh = lane >> 5;

    __shared__ u16 sX[16384];    // 32KB: x bf16 (preserved; residual source)
    __shared__ u16 sH[16384];    // 32KB: h (A->B), then x_out bf16 (B->C)
    __shared__ u16 sW[16384];    // 32KB: sWe+sWg+sWp (A) / Wup,Wdn chunk (B) / slice (C)
    __shared__ u16 sU[16384];    // 32KB: sD+sZ (A) / gelu (B) / P bounce (C)
    __shared__ float sMu[128], sRstd[128], sNrm[128], sNov[128];

    u16* sWe = sW;               // bytes [0,8192)
    u16* sWg = sW + 8192;        // bytes [16384,24576)
    u16* sWp = sW + 12288;       // bytes [24576,26624)
    u16* sD  = sU;               // [128][32] swz64, bytes [0,8192)
    u16* sZ  = sU + 4096;        // [128][32] swz64, bytes [8192,16384)

    const u16* wUp = ws + WUP_I + (size_t)g * 65536;
    const u16* wDn = ws + WDN_I + (size_t)g * 65536;
    const u16* wPo = ws + WPO_I + (size_t)g * 65664;

    // ---- stage x -> sX bf16 swz256; small-weight linear image copies ----
    for (int idx = tid; idx < 128 * 32; idx += 1024) {
        int row = idx >> 5, q = idx & 31;
        float4 v = *(const float4*)&x_col[(size_t)(m0 + row) * 8192 + g * 128 + q * 4];
        u16x4 bv; bv.x = f2b(v.x); bv.y = f2b(v.y); bv.z = f2b(v.z); bv.w = f2b(v.w);
        *(u16x4*)((char*)sX + swz256(row, q * 8)) = bv;
    }
    {
        const short8* se = (const short8*)(ws + WEN_I + (size_t)g * 4096);
        const short8* sg = (const short8*)(ws + WGN_I + (size_t)g * 4096);
        const short8* sp = (const short8*)(ws + WPR_I + (size_t)g * 1024);
        if (tid < 512) ((short8*)sWe)[tid] = se[tid];
        else           ((short8*)sWg)[tid - 512] = sg[tid - 512];
        if (tid < 128) ((short8*)sWp)[tid] = sp[tid];
    }
    if (tid < 128) sNov[tid] = b2f(wPo[65536 + tid]);

    // T14 prefetch: issue Wup[0] loads now; consumed at first B-chunk.
    short8 pfA, pfB;
    {
        const short8* su = (const short8*)wUp;
        pfA = su[tid]; pfB = su[tid + 1024];
    }
    __syncthreads();

    // ---- phase A step 1: {waves 0-3: enc GEMM} || {waves 4-11: LN stats} ----
    if (w16 < 4) {
        f32x16 zacc = (f32x16)0.f;
        #pragma unroll
        for (int ks = 0; ks < 8; ++ks)
            zacc = MFMA(fragLd256(sX, 32 * w16 + l31, ks), fragLd256(sWe, l31, ks), zacc);
        float benc = b_enc[g * 32 + l31];
        #pragma unroll
        for (int r = 0; r < 16; ++r) {
            float zv = zacc[r] + benc;
            int row = 32 * w16 + (r & 3) + 8 * (r >> 2) + 4 * lh;
            size_t zoff = (size_t)(m0 + row) * 2048 + g * 32 + l31;
            out[OFF_Z + zoff] = zv;
            float d = zv - z_hat_prev[zoff];
            *(u16*)((char*)sD + swz64(row, l31 * 2)) = f2b(d);
            *(u16*)((char*)sZ + swz64(row, l31 * 2)) = f2b(zv);
            float ss = d * d;
            ss += __shfl_xor(ss, 1); ss += __shfl_xor(ss, 2); ss += __shfl_xor(ss, 4);
            ss += __shfl_xor(ss, 8); ss += __shfl_xor(ss, 16);
            if (l31 == 0) {
                float sur = sqrtf(ss);
                size_t p = (size_t)(m0 + row) * 64 + g;
                out[OFF_SUR + p] = sur;
                out[OFF_S5 + p] = sur;
                out[OFF_GATE + p] = fminf(fmaxf(sur, 0.f), 1.f);
            }
        }
    } else if (w16 < 12) {
        int t = tid - 256;                    // 0..511: 4 threads per row
        int row = t >> 2, part = t & 3;
        float s1 = 0.f, s2 = 0.f;
        #pragma unroll
        for (int i = 0; i < 4; ++i) {
            short8 v = *(const short8*)((const char*)sX + swz256(row, (part * 32 + i * 8) * 2));
            #pragma unroll
            for (int jj = 0; jj < 8; ++jj) { float x = b2f((u16)v[jj]); s1 += x; s2 += x * x; }
        }
        s1 += __shfl_xor(s1, 1); s2 += __shfl_xor(s2, 1);
        s1 += __shfl_xor(s1, 2); s2 += __shfl_xor(s2, 2);
        if (part == 0) {
            float mu = s1 * (1.f / 128.f);
            float var = s2 * (1.f / 128.f) - mu * mu;
            sMu[row] = mu; sRstd[row] = rsqrtf(var + 1e-5f);
        }
    }
    __syncthreads();

    // ---- phase A step 2: {waves 0-7: gain GEMM + LN apply -> sH} || {waves 8-11: pred} ----
    if (w16 < 8) {
        const int wrg = w16 >> 1;
        const int cp  = w16 & 1;
        f32x16 gacc[2];
        gacc[0] = (f32x16)0.f; gacc[1] = (f32x16)0.f;
        #pragma unroll
        for (int ks = 0; ks < 2; ++ks) {
            short8 a = fragLd64(sD, 32 * wrg + l31, ks);
            #pragma unroll
            for (int k = 0; k < 2; ++k) {
                short8 b = fragLd64(sWg, 32 * (2 * cp + k) + l31, ks);
                gacc[k] = MFMA(a, b, gacc[k]);
            }
        }
        #pragma unroll
        for (int k = 0; k < 2; ++k) {
            int col = 32 * (2 * cp + k) + l31;
            float bg = b_gain[g * 128 + col];
            float gam = gamma[g * 128 + col];
            float bet = beta[g * 128 + col];
            #pragma unroll
            for (int r = 0; r < 16; ++r) {
                int row = 32 * wrg + (r & 3) + 8 * (r >> 2) + 4 * lh;
                float gain = 1.f + 0.1f * tanh_f(gacc[k][r] + bg);
                float xv = b2f(*(const u16*)((const char*)sX + swz256(row, col * 2)));
                float h = ((xv - sMu[row]) * sRstd[row] * gam + bet) * gain;
                *(u16*)((char*)sH + swz256(row, col * 2)) = f2b(h);
            }
        }
    } else if (w16 < 12) {
        int wp = w16 - 8;
        f32x16 pacc = (f32x16)0.f;
        #pragma unroll
        for (int ks = 0; ks < 2; ++ks) {
            short8 a = fragLd64(sZ, 32 * wp + l31, ks);
            short8 b = fragLd64(sWp, l31, ks);
            pacc = MFMA(a, b, pacc);
        }
        float bpred = b_pred[g * 32 + l31];
        #pragma unroll
        for (int r = 0; r < 16; ++r) {
            int row = 32 * wp + (r & 3) + 8 * (r >> 2) + 4 * lh;
            out[OFF_ZHAT + (size_t)(m0 + row) * 2048 + g * 32 + l31] = pacc[r] + bpred;
        }
    }
    // sH writes protected by the sync at the top of the first B-chunk.

    // ---- phase B: MLP, 4 chunks of 128 hidden cols; all staging prefetched ----
    f32x16 dacc = (f32x16)0.f;

    for (int ch = 0; ch < 4; ++ch) {
        __syncthreads();   // S0: sW readers (step-2 / prev down-MFMA) done; sH ready (ch0)
        ((short8*)sW)[tid]        = pfA;     // ds_write Wup[ch]
        ((short8*)sW)[tid + 1024] = pfB;
        {
            const short8* nxt = (const short8*)(wDn + ch * 16384);
            pfA = nxt[tid]; pfB = nxt[tid + 1024];   // issue Wdn[ch]; covered by up+gelu
        }
        __syncthreads();   // S1: Wup visible

        f32x16 uacc = (f32x16)0.f;
        #pragma unroll
        for (int ks = 0; ks < 8; ++ks)
            uacc = MFMA(fragLd256(sH, 32 * wr + l31, ks),
                        fragLd256(sW, 32 * wc + l31, ks), uacc);
        {
            float bup = b_up[(size_t)g * 512 + ch * 128 + 32 * wc + l31];
            int colB = (32 * wc + l31) * 2;
            #pragma unroll
            for (int r = 0; r < 16; ++r) {
                int row = 32 * wr + (r & 3) + 8 * (r >> 2) + 4 * lh;
                *(u16*)((char*)sU + swz256(row, colB)) = f2b(gelu_f(uacc[r] + bup));
            }
        }
        __syncthreads();   // S2: gelu in sU ready; sW (Wup) readers done
        ((short8*)sW)[tid]        = pfA;     // ds_write Wdn[ch]
        ((short8*)sW)[tid + 1024] = pfB;
        {
            const short8* nxt = (const short8*)((ch < 3) ? (wUp + (ch + 1) * 16384) : wPo);
            pfA = nxt[tid]; pfB = nxt[tid + 1024];   // issue next; covered by down-MFMA
        }
        __syncthreads();   // S3: Wdn visible
        #pragma unroll
        for (int ks = 0; ks < 8; ++ks)
            dacc = MFMA(fragLd256(sU, 32 * wr + l31, ks),
                        fragLd256(sW, 32 * wc + l31, ks), dacc);
    }

    // epilogue: x_out = x(sX) + b_down + mlp -> global f32 + sH bf16
    {
        int jc = 32 * wc + l31;
        float bd = b_down[g * 128 + jc];
        #pragma unroll
        for (int r = 0; r < 16; ++r) {
            int row = 32 * wr + (r & 3) + 8 * (r >> 2) + 4 * lh;
            size_t base = (size_t)(m0 + row) * 8192 + g * 128 + jc;
            float xo = b2f(*(const u16*)((const char*)sX + swz256(row, jc * 2)))
                       + bd + dacc[r];
            out[OFF_XOUT + base] = xo;
            *(u16*)((char*)sH + swz256(row, jc * 2)) = f2b(xo);
        }
    }

    // ---- phase C: post-proj; slice staging prefetched ----
    for (int s = 0; s < 4; ++s) {
        __syncthreads();   // C0: sH epilogue writes + prev-slice sU/sW readers done
        ((short8*)sW)[tid]        = pfA;     // ds_write slice s
        ((short8*)sW)[tid + 1024] = pfB;
        if (s < 3) {
            const short8* nxt = (const short8*)(wPo + (s + 1) * 16384);
            pfA = nxt[tid]; pfB = nxt[tid + 1024];   // covered by slice-s MFMA + stores
        }
        __syncthreads();   // C1: slice visible

        f32x16 acc = (f32x16)0.f;
        #pragma unroll
        for (int ks = 0; ks < 8; ++ks)
            acc = MFMA(fragLd256(sH, 32 * wr + l31, ks),
                       fragLd256(sW, 32 * wc + l31, ks), acc);
        {
            float bp = b_post[g * 513 + s * 128 + 32 * wc + l31];
            int colB = (32 * wc + l31) * 2;
            #pragma unroll
            for (int r = 0; r < 16; ++r) {
                int row = 32 * wr + (r & 3) + 8 * (r >> 2) + 4 * lh;
                *(u16*)((char*)sU + swz256(row, colB)) = f2b(acc[r] + bp);
            }
        }
        __syncthreads();

        const bool nrm = (s == 0 || s == 2);
        if (nrm) {
            int row = tid >> 3, part = tid & 7;
            float ss = 0.f;
            #pragma unroll
            for (int i = 0; i < 2; ++i) {
                short8 v = *(const short8*)((const char*)sU + swz256(row, (part * 16 + i * 8) * 2));
                #pragma unroll
                for (int jj = 0; jj < 8; ++jj) { float x = b2f((u16)v[jj]); ss += x * x; }
            }
            ss += __shfl_xor(ss, 1); ss += __shfl_xor(ss, 2); ss += __shfl_xor(ss, 4);
            if (part == 0) sNrm[row] = sqrtf(ss);
            __syncthreads();
        }
        size_t off = (s == 0) ? OFF_KC : (s == 1) ? OFF_VP : (s == 2) ? OFF_QN : OFF_VC;
        for (int idx = tid; idx < 128 * 16; idx += 1024) {
            int row = idx >> 4, slot = idx & 15;
            float inv = nrm ? __fdividef(1.f, sNrm[row] + 1e-6f) : 1.f;
            short8 v = *(const short8*)((const char*)sU + swz256(row, slot * 16));
            float4 o0, o1;
            o0.x = b2f((u16)v[0]) * inv; o0.y = b2f((u16)v[1]) * inv;
            o0.z = b2f((u16)v[2]) * inv; o0.w = b2f((u16)v[3]) * inv;
            o1.x = b2f((u16)v[4]) * inv; o1.y = b2f((u16)v[5]) * inv;
            o1.z = b2f((u16)v[6]) * inv; o1.w = b2f((u16)v[7]) * inv;
            size_t base = off + (size_t)(m0 + row) * 8192 + g * 128 + slot * 8;
            *(float4*)&out[base] = o0;
            *(float4*)&out[base + 4] = o1;
        }
    }
    __syncthreads();

    // nov column -> w_nov (x_out bf16 in sH)
    {
        int row = tid >> 3, part = tid & 7;
        float accn = 0.f;
        #pragma unroll
        for (int i = 0; i < 2; ++i) {
            short8 v = *(const short8*)((const char*)sH + swz256(row, (part * 16 + i * 8) * 2));
            #pragma unroll
            for (int jj = 0; jj < 8; ++jj) accn += b2f((u16)v[jj]) * sNov[part * 16 + i * 8 + jj];
        }
        accn += __shfl_xor(accn, 1); accn += __shfl_xor(accn, 2); accn += __shfl_xor(accn, 4);
        if (part == 0) {
            float nv = accn + b_post[g * 513 + 512];
            out[OFF_WN + (size_t)(m0 + row) * 64 + g] = __fdividef(1.f, 1.f + __expf(-nv));
        }
    }
}

extern "C" void kernel_launch(void* const* d_in, const int* in_sizes, int n_in,
                              void* d_out, int out_size, void* d_ws, size_t ws_size,
                              hipStream_t stream) {
    const float* x_col      = (const float*)d_in[0];
    const float* z_hat_prev = (const float*)d_in[1];
    const float* gamma      = (const float*)d_in[2];
    const float* beta       = (const float*)d_in[3];
    const float* W_up       = (const float*)d_in[4];
    const float* b_up       = (const float*)d_in[5];
    const float* W_down     = (const float*)d_in[6];
    const float* b_down     = (const float*)d_in[7];
    const float* W_post     = (const float*)d_in[8];
    const float* b_post     = (const float*)d_in[9];
    const float* W_enc      = (const float*)d_in[10];
    const float* b_enc      = (const float*)d_in[11];
    const float* W_pred     = (const float*)d_in[12];
    const float* b_pred     = (const float*)d_in[13];
    const float* W_gain     = (const float*)d_in[14];
    const float* b_gain     = (const float*)d_in[15];
    float* out = (float*)d_out;
    u16* ws = (u16*)d_ws;

    kconv_all<<<3520, 256, 0, stream>>>(W_up, W_down, W_post, W_enc, W_gain, W_pred, ws);
    kfused<<<1024, 1024, 0, stream>>>(x_col, z_hat_prev, gamma, beta,
                                      b_enc, b_pred, b_gain, b_up, b_down, b_post,
                                      ws, out);
}

// Round 14
// 281.010 us; speedup vs baseline: 1.1477x; 1.1477x over previous
//
#include <hip/hip_runtime.h>

typedef unsigned short u16;
typedef __attribute__((ext_vector_type(4))) unsigned short u16x4;
typedef __attribute__((ext_vector_type(8))) short short8;
typedef __attribute__((ext_vector_type(16))) float f32x16;

#define MFMA(a,b,c) __builtin_amdgcn_mfma_f32_32x32x16_bf16((a),(b),(c),0,0,0)

// ---- output offsets (floats), reference return order ----
static constexpr size_t OFF_XOUT = 0;
static constexpr size_t OFF_Z    = 16777216;
static constexpr size_t OFF_ZHAT = 20971520;
static constexpr size_t OFF_SUR  = 25165824;
static constexpr size_t OFF_KC   = 25296896;
static constexpr size_t OFF_VP   = 42074112;
static constexpr size_t OFF_GATE = 58851328;
static constexpr size_t OFF_QN   = 58982400;
static constexpr size_t OFF_VC   = 75759616;
static constexpr size_t OFF_WN   = 92536832;
static constexpr size_t OFF_S5   = 92667904;

// ---- workspace offsets (u16 elements): PRE-SWIZZLED bf16 weight images ----
static constexpr size_t WUP_I = 0;          // [G][4 chunks][32KB swz256 image of [128c][128k]]
static constexpr size_t WDN_I = 4194304;    // [G][4 chunks][32KB swz256 image of [128j][128c]]
static constexpr size_t WPO_I = 8388608;    // [G][4 slices][32KB image] + [128] nov col (65664/g)
static constexpr size_t WEN_I = 12591104;   // [G][8KB swz256 image of [32c][128k]]
static constexpr size_t WGN_I = 12853248;   // [G][8KB swz64 image of [128j][32k]]
static constexpr size_t WPR_I = 13115392;   // [G][2KB swz64 image of [32c][32k]]

// bit-math RNE bf16 convert (r12-proven codegen; do NOT use __float2bfloat16 —
// its NaN-branch implementation caused scratch spills in r13: FETCH 56->136MB)
__device__ __forceinline__ u16 f2b(float f) {
    unsigned u = __float_as_uint(f);
    unsigned r = (u + 0x7FFFu + ((u >> 16) & 1u)) >> 16;
    return (u16)r;
}
__device__ __forceinline__ float b2f(u16 b) {
    return __uint_as_float(((unsigned)b) << 16);
}
__device__ __forceinline__ int swz256(int row, int b) {
    return row * 256 + (b ^ ((row & 7) << 4) ^ (((row >> 3) & 1) << 7));
}
__device__ __forceinline__ int swz64(int row, int b) {
    return row * 64 + (b ^ ((row & 3) << 4));
}
__device__ __forceinline__ short8 fragLd256(const u16* s, int row, int ks) {
    int b = ks * 32 + ((threadIdx.x >> 5) & 1) * 16;
    return *(const short8*)((const char*)s + swz256(row, b));
}
__device__ __forceinline__ short8 fragLd64(const u16* s, int row, int ks) {
    int b = ks * 32 + ((threadIdx.x >> 5) & 1) * 16;
    return *(const short8*)((const char*)s + swz64(row, b));
}
__device__ __forceinline__ float tanh_f(float x) {
    float xc = fminf(fmaxf(x, -15.f), 15.f);
    float e = __expf(2.f * xc);
    return __fdividef(e - 1.f, e + 1.f);
}
// sigmoid-gelu: u*sigma(1.702u)
__device__ __forceinline__ float gelu_f(float u) {
    return __fdividef(u, 1.f + __expf(-1.702f * u));
}

// dst element index inside a group's image for source element (k, c)
__device__ __forceinline__ size_t mapElem(int wt, int k, int c) {
    switch (wt) {
    case 0: return (size_t)(c >> 7) * 16384 + (swz256(c & 127, 2 * k) >> 1);          // W_up
    case 1: return (size_t)(k >> 7) * 16384 + (swz256(c, 2 * (k & 127)) >> 1);        // W_down
    case 2: return (c == 512) ? (size_t)65536 + k
                              : (size_t)(c >> 7) * 16384 + (swz256(c & 127, 2 * k) >> 1); // W_post
    case 3: return (size_t)(swz256(c, 2 * k) >> 1);                                   // W_enc
    case 4: return (size_t)(swz64(c, 2 * k) >> 1);                                    // W_gain
    default: return (size_t)(swz64(c, 2 * k) >> 1);                                   // W_pred
    }
}

// ---------------- transpose + convert + swizzle for all six weights ----------------
// 8 consecutive k at fixed c map to one aligned 16B block in every image
// (swizzle XOR bits are >= bit 4), so writes are vectorized short8 stores.
// (r13-verified correct on HW.)
__global__ __launch_bounds__(256)
void kconv_all(const float* __restrict__ W_up, const float* __restrict__ W_down,
               const float* __restrict__ W_post, const float* __restrict__ W_enc,
               const float* __restrict__ W_gain, const float* __restrict__ W_pred,
               u16* __restrict__ ws)
{
    int b = blockIdx.x;
    const float* src; u16* dst; int K, C, bx, wt; size_t gstride;
    if (b < 1024)      { src = W_up;   dst = ws + WUP_I; K = 128; C = 512; bx = 8; wt = 0; gstride = 65536; }
    else if (b < 2048) { b -= 1024; src = W_down; dst = ws + WDN_I; K = 512; C = 128; bx = 2; wt = 1; gstride = 65536; }
    else if (b < 3200) { b -= 2048; src = W_post; dst = ws + WPO_I; K = 128; C = 513; bx = 9; wt = 2; gstride = 65664; }
    else if (b < 3328) { b -= 3200; src = W_enc;  dst = ws + WEN_I; K = 128; C = 32;  bx = 1; wt = 3; gstride = 4096; }
    else if (b < 3456) { b -= 3328; src = W_gain; dst = ws + WGN_I; K = 32;  C = 128; bx = 2; wt = 4; gstride = 4096; }
    else               { b -= 3456; src = W_pred; dst = ws + WPR_I; K = 32;  C = 32;  bx = 1; wt = 5; gstride = 1024; }
    const int by = (K + 63) >> 6;
    const int nb = bx * by;
    const int g = b / nb, r = b % nb;
    const int c0 = (r % bx) * 64, k0 = (r / bx) * 64;

    __shared__ float sT[64][65];
    const float* s = src + (size_t)g * K * C;
    u16* d = dst + (size_t)g * gstride;
    for (int e = threadIdx.x; e < 64 * 64; e += 256) {
        int kk = e >> 6, cc = e & 63;
        if (k0 + kk < K && c0 + cc < C)
            sT[kk][cc] = s[(size_t)(k0 + kk) * C + c0 + cc];
    }
    __syncthreads();
    // vectorized: 64 cols x 8 k-blocks per tile, one short8 store each
    for (int e = threadIdx.x; e < 512; e += 256) {
        int cc = e & 63, kb = e >> 6;
        int c = c0 + cc, k = k0 + kb * 8;
        if (c < C && c != 512 && k + 7 < K) {
            short8 v;
            #pragma unroll
            for (int i = 0; i < 8; ++i) v[i] = (short)f2b(sT[kb * 8 + i][cc]);
            *(short8*)(d + mapElem(wt, k, c)) = v;
        }
    }
    if (wt == 2 && c0 == 512) {   // nov column scalar path
        for (int kk = threadIdx.x; kk < 64; kk += 256) {
            int k = k0 + kk;
            if (k < K) d[(size_t)65536 + k] = f2b(sT[kk][0]);
        }
    }
}

// ---------------- fused main: r12 kernel verbatim (262us proven) ----------------
__global__ __launch_bounds__(1024, 4)
void kfused(const float* __restrict__ x_col,
            const float* __restrict__ z_hat_prev,
            const float* __restrict__ gamma,
            const float* __restrict__ beta,
            const float* __restrict__ b_enc,
            const float* __restrict__ b_pred,
            const float* __restrict__ b_gain,
            const float* __restrict__ b_up,
            const float* __restrict__ b_down,
            const float* __restrict__ b_post,
            const u16* __restrict__ ws,
            float* __restrict__ out)
{
    const int bid = blockIdx.x;
    const int xc = bid & 7, j = bid >> 3;
    const int g = xc * 8 + (j >> 4);
    const int tile = j & 15;
    const int m0 = tile * 128;

    const int tid = threadIdx.x, lane = tid & 63;
    const int w16 = tid >> 6;                // wave 0..15
    const int wr = w16 >> 2;                 // row frag (32 rows)
    const int wc = w16 & 3;                  // col frag (32 cols)
    const int l31 = lane & 31, lh = lane >> 5;

    __shared__ u16 sX[16384];    // 32KB: x bf16 (preserved; residual source)
    __shared__ u16 sH[16384];    // 32KB: h (A->B), then x_out bf16 (B->C)
    __shared__ u16 sW[16384];    // 32KB: sWe+sWg+sWp (A) / Wup,Wdn chunk (B) / slice (C)
    __shared__ u16 sU[16384];    // 32KB: sD+sZ (A) / gelu (B) / P bounce (C)
    __shared__ float sMu[128], sRstd[128], sNrm[128], sNov[128];

    u16* sWe = sW;               // bytes [0,8192)
    u16* sWg = sW + 8192;        // bytes [16384,24576)
    u16* sWp = sW + 12288;       // bytes [24576,26624)
    u16* sD  = sU;               // [128][32] swz64, bytes [0,8192)
    u16* sZ  = sU + 4096;        // [128][32] swz64, bytes [8192,16384)

    const u16* wUp = ws + WUP_I + (size_t)g * 65536;
    const u16* wDn = ws + WDN_I + (size_t)g * 65536;
    const u16* wPo = ws + WPO_I + (size_t)g * 65664;

    // ---- stage x -> sX bf16 swz256; small-weight linear image copies ----
    for (int idx = tid; idx < 128 * 32; idx += 1024) {
        int row = idx >> 5, q = idx & 31;
        float4 v = *(const float4*)&x_col[(size_t)(m0 + row) * 8192 + g * 128 + q * 4];
        u16x4 bv; bv.x = f2b(v.x); bv.y = f2b(v.y); bv.z = f2b(v.z); bv.w = f2b(v.w);
        *(u16x4*)((char*)sX + swz256(row, q * 8)) = bv;
    }
    {
        const short8* se = (const short8*)(ws + WEN_I + (size_t)g * 4096);
        const short8* sg = (const short8*)(ws + WGN_I + (size_t)g * 4096);
        const short8* sp = (const short8*)(ws + WPR_I + (size_t)g * 1024);
        if (tid < 512) ((short8*)sWe)[tid] = se[tid];
        else           ((short8*)sWg)[tid - 512] = sg[tid - 512];
        if (tid < 128) ((short8*)sWp)[tid] = sp[tid];
    }
    if (tid < 128) sNov[tid] = b2f(wPo[65536 + tid]);

    // T14 prefetch: issue Wup[0] loads now; consumed at first B-chunk.
    short8 pfA, pfB;
    {
        const short8* su = (const short8*)wUp;
        pfA = su[tid]; pfB = su[tid + 1024];
    }
    __syncthreads();

    // ---- phase A step 1: {waves 0-3: enc GEMM} || {waves 4-7: LN stats} ----
    if (w16 < 4) {
        f32x16 zacc = (f32x16)0.f;
        #pragma unroll
        for (int ks = 0; ks < 8; ++ks)
            zacc = MFMA(fragLd256(sX, 32 * w16 + l31, ks), fragLd256(sWe, l31, ks), zacc);
        float benc = b_enc[g * 32 + l31];
        #pragma unroll
        for (int r = 0; r < 16; ++r) {
            float zv = zacc[r] + benc;
            int row = 32 * w16 + (r & 3) + 8 * (r >> 2) + 4 * lh;
            size_t zoff = (size_t)(m0 + row) * 2048 + g * 32 + l31;
            out[OFF_Z + zoff] = zv;
            float d = zv - z_hat_prev[zoff];
            *(u16*)((char*)sD + swz64(row, l31 * 2)) = f2b(d);
            *(u16*)((char*)sZ + swz64(row, l31 * 2)) = f2b(zv);
            float ss = d * d;
            ss += __shfl_xor(ss, 1); ss += __shfl_xor(ss, 2); ss += __shfl_xor(ss, 4);
            ss += __shfl_xor(ss, 8); ss += __shfl_xor(ss, 16);
            if (l31 == 0) {
                float sur = sqrtf(ss);
                size_t p = (size_t)(m0 + row) * 64 + g;
                out[OFF_SUR + p] = sur;
                out[OFF_S5 + p] = sur;
                out[OFF_GATE + p] = fminf(fmaxf(sur, 0.f), 1.f);
            }
        }
    } else if (w16 < 8) {
        int t = tid - 256;
        int row = t >> 1, half = t & 1;
        float s1 = 0.f, s2 = 0.f;
        #pragma unroll
        for (int i = 0; i < 8; ++i) {
            short8 v = *(const short8*)((const char*)sX + swz256(row, (half * 64 + i * 8) * 2));
            #pragma unroll
            for (int jj = 0; jj < 8; ++jj) { float x = b2f((u16)v[jj]); s1 += x; s2 += x * x; }
        }
        s1 += __shfl_xor(s1, 1); s2 += __shfl_xor(s2, 1);
        if (half == 0) {
            float mu = s1 * (1.f / 128.f);
            float var = s2 * (1.f / 128.f) - mu * mu;
            sMu[row] = mu; sRstd[row] = rsqrtf(var + 1e-5f);
        }
    }
    __syncthreads();

    // ---- phase A step 2: {waves 0-7: gain GEMM + LN apply -> sH} || {waves 8-11: pred} ----
    if (w16 < 8) {
        const int wrg = w16 >> 1;
        const int cp  = w16 & 1;
        f32x16 gacc[2];
        gacc[0] = (f32x16)0.f; gacc[1] = (f32x16)0.f;
        #pragma unroll
        for (int ks = 0; ks < 2; ++ks) {
            short8 a = fragLd64(sD, 32 * wrg + l31, ks);
            #pragma unroll
            for (int k = 0; k < 2; ++k) {
                short8 b = fragLd64(sWg, 32 * (2 * cp + k) + l31, ks);
                gacc[k] = MFMA(a, b, gacc[k]);
            }
        }
        #pragma unroll
        for (int k = 0; k < 2; ++k) {
            int col = 32 * (2 * cp + k) + l31;
            float bg = b_gain[g * 128 + col];
            float gam = gamma[g * 128 + col];
            float bet = beta[g * 128 + col];
            #pragma unroll
            for (int r = 0; r < 16; ++r) {
                int row = 32 * wrg + (r & 3) + 8 * (r >> 2) + 4 * lh;
                float gain = 1.f + 0.1f * tanh_f(gacc[k][r] + bg);
                float xv = b2f(*(const u16*)((const char*)sX + swz256(row, col * 2)));
                float h = ((xv - sMu[row]) * sRstd[row] * gam + bet) * gain;
                *(u16*)((char*)sH + swz256(row, col * 2)) = f2b(h);
            }
        }
    } else if (w16 < 12) {
        int wp = w16 - 8;
        f32x16 pacc = (f32x16)0.f;
        #pragma unroll
        for (int ks = 0; ks < 2; ++ks) {
            short8 a = fragLd64(sZ, 32 * wp + l31, ks);
            short8 b = fragLd64(sWp, l31, ks);
            pacc = MFMA(a, b, pacc);
        }
        float bpred = b_pred[g * 32 + l31];
        #pragma unroll
        for (int r = 0; r < 16; ++r) {
            int row = 32 * wp + (r & 3) + 8 * (r >> 2) + 4 * lh;
            out[OFF_ZHAT + (size_t)(m0 + row) * 2048 + g * 32 + l31] = pacc[r] + bpred;
        }
    }
    // sH writes protected by the sync at the top of the first B-chunk.

    // ---- phase B: MLP, 4 chunks of 128 hidden cols; all staging prefetched ----
    f32x16 dacc = (f32x16)0.f;

    for (int ch = 0; ch < 4; ++ch) {
        __syncthreads();   // S0: sW readers (step-2 / prev down-MFMA) done; sH ready (ch0)
        ((short8*)sW)[tid]        = pfA;     // ds_write Wup[ch]
        ((short8*)sW)[tid + 1024] = pfB;
        {
            const short8* nxt = (const short8*)(wDn + ch * 16384);
            pfA = nxt[tid]; pfB = nxt[tid + 1024];   // issue Wdn[ch]; covered by up+gelu
        }
        __syncthreads();   // S1: Wup visible

        f32x16 uacc = (f32x16)0.f;
        #pragma unroll
        for (int ks = 0; ks < 8; ++ks)
            uacc = MFMA(fragLd256(sH, 32 * wr + l31, ks),
                        fragLd256(sW, 32 * wc + l31, ks), uacc);
        {
            float bup = b_up[(size_t)g * 512 + ch * 128 + 32 * wc + l31];
            int colB = (32 * wc + l31) * 2;
            #pragma unroll
            for (int r = 0; r < 16; ++r) {
                int row = 32 * wr + (r & 3) + 8 * (r >> 2) + 4 * lh;
                *(u16*)((char*)sU + swz256(row, colB)) = f2b(gelu_f(uacc[r] + bup));
            }
        }
        __syncthreads();   // S2: gelu in sU ready; sW (Wup) readers done
        ((short8*)sW)[tid]        = pfA;     // ds_write Wdn[ch]
        ((short8*)sW)[tid + 1024] = pfB;
        {
            const short8* nxt = (const short8*)((ch < 3) ? (wUp + (ch + 1) * 16384) : wPo);
            pfA = nxt[tid]; pfB = nxt[tid + 1024];   // issue next; covered by down-MFMA
        }
        __syncthreads();   // S3: Wdn visible
        #pragma unroll
        for (int ks = 0; ks < 8; ++ks)
            dacc = MFMA(fragLd256(sU, 32 * wr + l31, ks),
                        fragLd256(sW, 32 * wc + l31, ks), dacc);
    }

    // epilogue: x_out = x(sX) + b_down + mlp -> global f32 + sH bf16
    {
        int jc = 32 * wc + l31;
        float bd = b_down[g * 128 + jc];
        #pragma unroll
        for (int r = 0; r < 16; ++r) {
            int row = 32 * wr + (r & 3) + 8 * (r >> 2) + 4 * lh;
            size_t base = (size_t)(m0 + row) * 8192 + g * 128 + jc;
            float xo = b2f(*(const u16*)((const char*)sX + swz256(row, jc * 2)))
                       + bd + dacc[r];
            out[OFF_XOUT + base] = xo;
            *(u16*)((char*)sH + swz256(row, jc * 2)) = f2b(xo);
        }
    }

    // ---- phase C: post-proj; slice staging prefetched ----
    for (int s = 0; s < 4; ++s) {
        __syncthreads();   // C0: sH epilogue writes + prev-slice sU/sW readers done
        ((short8*)sW)[tid]        = pfA;     // ds_write slice s
        ((short8*)sW)[tid + 1024] = pfB;
        if (s < 3) {
            const short8* nxt = (const short8*)(wPo + (s + 1) * 16384);
            pfA = nxt[tid]; pfB = nxt[tid + 1024];   // covered by slice-s MFMA + stores
        }
        __syncthreads();   // C1: slice visible

        f32x16 acc = (f32x16)0.f;
        #pragma unroll
        for (int ks = 0; ks < 8; ++ks)
            acc = MFMA(fragLd256(sH, 32 * wr + l31, ks),
                       fragLd256(sW, 32 * wc + l31, ks), acc);
        {
            float bp = b_post[g * 513 + s * 128 + 32 * wc + l31];
            int colB = (32 * wc + l31) * 2;
            #pragma unroll
            for (int r = 0; r < 16; ++r) {
                int row = 32 * wr + (r & 3) + 8 * (r >> 2) + 4 * lh;
                *(u16*)((char*)sU + swz256(row, colB)) = f2b(acc[r] + bp);
            }
        }
        __syncthreads();

        const bool nrm = (s == 0 || s == 2);
        if (nrm) {
            int row = tid >> 3, part = tid & 7;
            float ss = 0.f;
            #pragma unroll
            for (int i = 0; i < 2; ++i) {
                short8 v = *(const short8*)((const char*)sU + swz256(row, (part * 16 + i * 8) * 2));
                #pragma unroll
                for (int jj = 0; jj < 8; ++jj) { float x = b2f((u16)v[jj]); ss += x * x; }
            }
            ss += __shfl_xor(ss, 1); ss += __shfl_xor(ss, 2); ss += __shfl_xor(ss, 4);
            if (part == 0) sNrm[row] = sqrtf(ss);
            __syncthreads();
        }
        size_t off = (s == 0) ? OFF_KC : (s == 1) ? OFF_VP : (s == 2) ? OFF_QN : OFF_VC;
        for (int idx = tid; idx < 128 * 16; idx += 1024) {
            int row = idx >> 4, slot = idx & 15;
            float inv = nrm ? __fdividef(1.f, sNrm[row] + 1e-6f) : 1.f;
            short8 v = *(const short8*)((const char*)sU + swz256(row, slot * 16));
            float4 o0, o1;
            o0.x = b2f((u16)v[0]) * inv; o0.y = b2f((u16)v[1]) * inv;
            o0.z = b2f((u16)v[2]) * inv; o0.w = b2f((u16)v[3]) * inv;
            o1.x = b2f((u16)v[4]) * inv; o1.y = b2f((u16)v[5]) * inv;
            o1.z = b2f((u16)v[6]) * inv; o1.w = b2f((u16)v[7]) * inv;
            size_t base = off + (size_t)(m0 + row) * 8192 + g * 128 + slot * 8;
            *(float4*)&out[base] = o0;
            *(float4*)&out[base + 4] = o1;
        }
    }
    __syncthreads();

    // nov column -> w_nov (x_out bf16 in sH)
    {
        int row = tid >> 3, part = tid & 7;
        float accn = 0.f;
        #pragma unroll
        for (int i = 0; i < 2; ++i) {
            short8 v = *(const short8*)((const char*)sH + swz256(row, (part * 16 + i * 8) * 2));
            #pragma unroll
            for (int jj = 0; jj < 8; ++jj) accn += b2f((u16)v[jj]) * sNov[part * 16 + i * 8 + jj];
        }
        accn += __shfl_xor(accn, 1); accn += __shfl_xor(accn, 2); accn += __shfl_xor(accn, 4);
        if (part == 0) {
            float nv = accn + b_post[g * 513 + 512];
            out[OFF_WN + (size_t)(m0 + row) * 64 + g] = __fdividef(1.f, 1.f + __expf(-nv));
        }
    }
}

extern "C" void kernel_launch(void* const* d_in, const int* in_sizes, int n_in,
                              void* d_out, int out_size, void* d_ws, size_t ws_size,
                              hipStream_t stream) {
    const float* x_col      = (const float*)d_in[0];
    const float* z_hat_prev = (const float*)d_in[1];
    const float* gamma      = (const float*)d_in[2];
    const float* beta       = (const float*)d_in[3];
    const float* W_up       = (const float*)d_in[4];
    const float* b_up       = (const float*)d_in[5];
    const float* W_down     = (const float*)d_in[6];
    const float* b_down     = (const float*)d_in[7];
    const float* W_post     = (const float*)d_in[8];
    const float* b_post     = (const float*)d_in[9];
    const float* W_enc      = (const float*)d_in[10];
    const float* b_enc      = (const float*)d_in[11];
    const float* W_pred     = (const float*)d_in[12];
    const float* b_pred     = (const float*)d_in[13];
    const float* W_gain     = (const float*)d_in[14];
    const float* b_gain     = (const float*)d_in[15];
    float* out = (float*)d_out;
    u16* ws = (u16*)d_ws;

    kconv_all<<<3520, 256, 0, stream>>>(W_up, W_down, W_post, W_enc, W_gain, W_pred, ws);
    kfused<<<1024, 1024, 0, stream>>>(x_col, z_hat_prev, gamma, beta,
                                      b_enc, b_pred, b_gain, b_up, b_down, b_post,
                                      ws, out);
}